// Round 1
// baseline (11602.923 us; speedup 1.0000x reference)
//
#include <hip/hip_runtime.h>
#include <stdint.h>

#define B_ 32
#define T_ 128
#define S_ 256
#define D_ 1024
#define V_ 10000

typedef unsigned short u16;
typedef __attribute__((ext_vector_type(8))) short bf16x8;   // 8 bf16 in 4 VGPRs
typedef __attribute__((ext_vector_type(4))) float f32x4;

__device__ __forceinline__ float bf2f(u16 u){ union { unsigned int i; float f; } v; v.i = ((unsigned int)u)<<16; return v.f; }
__device__ __forceinline__ u16 f2bf(float f){ union { float ff; unsigned int i; } v; v.ff = f; unsigned int x = v.i; return (u16)((x + 0x7fffu + ((x>>16)&1u))>>16); }
__device__ __forceinline__ float sigm(float x){ return 1.f/(1.f+__expf(-x)); }
__device__ __forceinline__ float ftanh(float x){ x = fminf(fmaxf(x,-15.f),15.f); float e=__expf(2.f*x); return (e-1.f)/(e+1.f); }

// ---------------- prep kernels ----------------
__global__ void k_cast(const float* __restrict__ in, u16* __restrict__ out, long n){
  for (long i = (long)blockIdx.x*blockDim.x + threadIdx.x; i < n; i += (long)gridDim.x*blockDim.x)
    out[i] = f2bf(in[i]);
}

__global__ void k_w1cat(const float* __restrict__ wih1, const float* __restrict__ whh1, u16* __restrict__ out){
  const long n = (long)4096*2048;
  for (long i = (long)blockIdx.x*blockDim.x + threadIdx.x; i < n; i += (long)gridDim.x*blockDim.x){
    int row = (int)(i >> 11), k = (int)(i & 2047);
    float v = (k < D_) ? wih1[(size_t)row*D_ + k] : whh1[(size_t)row*D_ + (k - D_)];
    out[i] = f2bf(v);
  }
}

__global__ void k_bias(const float* __restrict__ bih, const float* __restrict__ bhh,
                       const float* __restrict__ bcv, const float* __restrict__ abias,
                       const float* __restrict__ Wcv, const float* __restrict__ fcw,
                       float* __restrict__ bias0, float* __restrict__ bias1,
                       float* __restrict__ biasE, float* __restrict__ convw){
  int i = blockIdx.x*blockDim.x + threadIdx.x;
  if (i < 4096){ bias0[i] = bih[i]+bhh[i]; bias1[i] = bih[4096+i]+bhh[4096+i]; }
  if (i < 1024){
    biasE[i] = bcv[i]+abias[i];
    convw[i*4+0]=Wcv[i*3+0]; convw[i*4+1]=Wcv[i*3+1]; convw[i*4+2]=Wcv[i*3+2]; convw[i*4+3]=fcw[i];
  }
}

__global__ void k_gather(const float* __restrict__ emb, const int* __restrict__ tgt, u16* __restrict__ embA){
  int row = blockIdx.x;            // row = t*32 + b
  int t = row >> 5, b = row & 31;
  int e = tgt[b*T_ + t];
  const float* src = emb + (size_t)e*D_;
  u16* dst = embA + (size_t)row*D_;
  for (int d = threadIdx.x; d < D_; d += 256) dst[d] = f2bf(src[d]);
}

// ---------------- big MFMA GEMM: C = A(MxK) @ B(NxK)^T (+bias)(+act) ----------------
__device__ __forceinline__ void gld_lds(const u16* g, u16* l){
  __builtin_amdgcn_global_load_lds((const __attribute__((address_space(1))) unsigned int*)g,
                                   (__attribute__((address_space(3))) unsigned int*)l, 16, 0, 0);
}

template<int OUT_MODE, bool SWIZ>   // OUT_MODE: 0 f32, 1 bf16, 2 tanh->bf16 ; SWIZ: row(t*32+b)->(b*128+t)
__global__ __launch_bounds__(256) void k_gemm128(const u16* __restrict__ Am, const u16* __restrict__ Bm,
      const float* __restrict__ bias, void* __restrict__ Cout, int M, int N, int K, int ldc)
{
  __shared__ u16 As[128*32];
  __shared__ u16 Bs[128*32];
  int bm = blockIdx.y*128, bn = blockIdx.x*128;
  int tid = threadIdx.x;
  int wv = tid>>6, lane = tid&63;
  int wm = (wv>>1)*64, wn = (wv&1)*64;
  int r = lane&15, kh = lane>>4;
  f32x4 zero = {0.f,0.f,0.f,0.f};
  f32x4 acc[4][4];
  #pragma unroll
  for (int mi=0;mi<4;mi++)
    #pragma unroll
    for (int ni=0;ni<4;ni++) acc[mi][ni] = zero;

  for (int k0 = 0; k0 < K; k0 += 32){
    #pragma unroll
    for (int i=0;i<2;i++){
      int c = tid + i*256;
      int row = c>>2, ko = (c&3)*8;
      int ga = bm+row; if (ga > M-1) ga = M-1;
      gld_lds(Am + (size_t)ga*K + k0 + ko, As + c*8);
      int gb = bn+row; if (gb > N-1) gb = N-1;
      gld_lds(Bm + (size_t)gb*K + k0 + ko, Bs + c*8);
    }
    __syncthreads();
    bf16x8 af[4], bfv[4];
    #pragma unroll
    for (int mi=0;mi<4;mi++) af[mi]  = *(const bf16x8*)(As + (wm+mi*16+r)*32 + kh*8);
    #pragma unroll
    for (int ni=0;ni<4;ni++) bfv[ni] = *(const bf16x8*)(Bs + (wn+ni*16+r)*32 + kh*8);
    #pragma unroll
    for (int mi=0;mi<4;mi++)
      #pragma unroll
      for (int ni=0;ni<4;ni++)
        acc[mi][ni] = __builtin_amdgcn_mfma_f32_16x16x32_bf16(af[mi], bfv[ni], acc[mi][ni], 0,0,0);
    __syncthreads();
  }
  #pragma unroll
  for (int mi=0;mi<4;mi++)
    #pragma unroll
    for (int ni=0;ni<4;ni++)
      #pragma unroll
      for (int rr=0;rr<4;rr++){
        int grow = bm+wm+mi*16+kh*4+rr;
        int gcol = bn+wn+ni*16+r;
        if (grow < M && gcol < N){
          float v = acc[mi][ni][rr];
          if (bias) v += bias[gcol];
          size_t orow = SWIZ ? (size_t)((grow&31)*T_ + (grow>>5)) : (size_t)grow;
          if (OUT_MODE==0)      ((float*)Cout)[orow*(size_t)ldc + gcol] = v;
          else if (OUT_MODE==1) ((u16*)Cout)[orow*(size_t)ldc + gcol] = f2bf(v);
          else                  ((u16*)Cout)[orow*(size_t)ldc + gcol] = f2bf(ftanh(v));
        }
      }
}

// ---------------- skinny GEMM core: (32 x K) @ B(N x K)^T, wave computes 16 cols x 32 rows ----------------
template<int K0, int K1>
__device__ __forceinline__ void skinny_mm(const u16* __restrict__ A0, const u16* __restrict__ A1,
     const u16* __restrict__ Bm, int ldb, int n0, f32x4& acc0, f32x4& acc1)
{
  int lane = threadIdx.x&63;
  int r = lane&15, kh = lane>>4;
  const u16* brow = Bm + (size_t)(n0+r)*ldb + kh*8;
  {
    const u16* a0r  = A0 + r*K0 + kh*8;
    const u16* a0r2 = A0 + (16+r)*K0 + kh*8;
    #pragma unroll 4
    for (int k=0;k<K0;k+=32){
      bf16x8 bv = *(const bf16x8*)(brow + k);
      bf16x8 a0 = *(const bf16x8*)(a0r + k);
      bf16x8 a1 = *(const bf16x8*)(a0r2 + k);
      acc0 = __builtin_amdgcn_mfma_f32_16x16x32_bf16(a0, bv, acc0, 0,0,0);
      acc1 = __builtin_amdgcn_mfma_f32_16x16x32_bf16(a1, bv, acc1, 0,0,0);
    }
  }
  if constexpr (K1 > 0){
    const u16* a1r  = A1 + r*K1 + kh*8;
    const u16* a1r2 = A1 + (16+r)*K1 + kh*8;
    #pragma unroll 4
    for (int k=0;k<K1;k+=32){
      bf16x8 bv = *(const bf16x8*)(brow + K0 + k);
      bf16x8 a0 = *(const bf16x8*)(a1r + k);
      bf16x8 a1 = *(const bf16x8*)(a1r2 + k);
      acc0 = __builtin_amdgcn_mfma_f32_16x16x32_bf16(a0, bv, acc0, 0,0,0);
      acc1 = __builtin_amdgcn_mfma_f32_16x16x32_bf16(a1, bv, acc1, 0,0,0);
    }
  }
}

// gates0 + LSTM cell 0. wave w = gate w, block wg covers hidden [wg*16, wg*16+16)
__global__ __launch_bounds__(256) void k_gates0(const u16* __restrict__ hA_in, const u16* __restrict__ Whh0,
    const u16* __restrict__ X0t, float* __restrict__ c0, u16* __restrict__ hA_out)
{
  __shared__ float gl[4][32][16];
  int wg = blockIdx.x;
  int w = threadIdx.x>>6, lane = threadIdx.x&63;
  int r = lane&15, kh = lane>>4;
  int n0 = w*D_ + wg*16;
  f32x4 acc0 = {0.f,0.f,0.f,0.f}, acc1 = {0.f,0.f,0.f,0.f};
  skinny_mm<1024,0>(hA_in, nullptr, Whh0, D_, n0, acc0, acc1);
  #pragma unroll
  for (int rr=0;rr<4;rr++){
    int b0 = kh*4+rr;
    gl[w][b0][r]    = acc0[rr] + bf2f(X0t[(size_t)b0*(4*D_) + n0 + r]);
    gl[w][16+b0][r] = acc1[rr] + bf2f(X0t[(size_t)(16+b0)*(4*D_) + n0 + r]);
  }
  __syncthreads();
  for (int pp = threadIdx.x; pp < 512; pp += 256){
    int b = pp>>4, j = pp&15;
    float gi = gl[0][b][j], gf = gl[1][b][j], gg = gl[2][b][j], go = gl[3][b][j];
    int idx = b*D_ + wg*16 + j;
    float cn = sigm(gf)*c0[idx] + sigm(gi)*ftanh(gg);
    float hn = sigm(go)*ftanh(cn);
    c0[idx] = cn;
    hA_out[idx] = f2bf(hn);
  }
}

// gates1 (input [h0_new | h1_old] vs W1cat) + LSTM cell 1; also writes q into qcat[:, 0:1024]
__global__ __launch_bounds__(256) void k_gates1(const u16* __restrict__ h0new, const u16* __restrict__ h1old,
    const u16* __restrict__ W1cat, const float* __restrict__ bias1, float* __restrict__ c1,
    u16* __restrict__ hB_out, u16* __restrict__ qcat_t)
{
  __shared__ float gl[4][32][16];
  int wg = blockIdx.x;
  int w = threadIdx.x>>6, lane = threadIdx.x&63;
  int r = lane&15, kh = lane>>4;
  int n0 = w*D_ + wg*16;
  f32x4 acc0 = {0.f,0.f,0.f,0.f}, acc1 = {0.f,0.f,0.f,0.f};
  skinny_mm<1024,1024>(h0new, h1old, W1cat, 2048, n0, acc0, acc1);
  #pragma unroll
  for (int rr=0;rr<4;rr++){
    float bi = bias1[n0+r];
    gl[w][kh*4+rr][r]    = acc0[rr] + bi;
    gl[w][16+kh*4+rr][r] = acc1[rr] + bi;
  }
  __syncthreads();
  for (int pp = threadIdx.x; pp < 512; pp += 256){
    int b = pp>>4, j = pp&15;
    float gi = gl[0][b][j], gf = gl[1][b][j], gg = gl[2][b][j], go = gl[3][b][j];
    int idx = b*D_ + wg*16 + j;
    float cn = sigm(gf)*c1[idx] + sigm(gi)*ftanh(gg);
    float hn = sigm(go)*ftanh(cn);
    c1[idx] = cn;
    u16 hb = f2bf(hn);
    hB_out[idx] = hb;
    qcat_t[b*2048 + wg*16 + j] = hb;
  }
}

__global__ __launch_bounds__(256) void k_qp(const u16* __restrict__ hB, const u16* __restrict__ Wq, float* __restrict__ qp)
{
  int wv = threadIdx.x>>6, lane = threadIdx.x&63;
  int r = lane&15, kh = lane>>4;
  int n0 = blockIdx.x*64 + wv*16;
  f32x4 acc0 = {0.f,0.f,0.f,0.f}, acc1 = {0.f,0.f,0.f,0.f};
  skinny_mm<1024,0>(hB, nullptr, Wq, D_, n0, acc0, acc1);
  #pragma unroll
  for (int rr=0;rr<4;rr++){
    qp[(kh*4+rr)*D_ + n0 + r]      = acc0[rr];
    qp[(16+kh*4+rr)*D_ + n0 + r]   = acc1[rr];
  }
}

// energy[b,s] = sum_d tanh(qp[b,d] + vpb[b,s,d] + conv(attn)[b,s,d]) * fcw[d]   (one wave per (b,s))
__global__ __launch_bounds__(256) void k_energy(const u16* __restrict__ vpb, const float* __restrict__ qp,
    const float* __restrict__ attn_prev, const float* __restrict__ convw, float* __restrict__ energy)
{
  int w = threadIdx.x>>6, lane = threadIdx.x&63;
  int gw = blockIdx.x*4 + w;
  int b = gw >> 8, s = gw & 255;
  int d0 = lane*16;
  const bf16x8* vp8 = (const bf16x8*)(vpb + ((size_t)(b*S_+s))*D_ + d0);
  const f32x4*  qp4 = (const f32x4*)(qp + b*D_ + d0);
  const f32x4*  cw4 = (const f32x4*)(convw + (size_t)d0*4);
  float am = (s>0)      ? attn_prev[b*S_+s-1] : 0.f;
  float ac =              attn_prev[b*S_+s];
  float ap = (s<S_-1)   ? attn_prev[b*S_+s+1] : 0.f;
  bf16x8 v0 = vp8[0], v1 = vp8[1];
  f32x4 q0 = qp4[0], q1 = qp4[1], q2 = qp4[2], q3 = qp4[3];
  float sum = 0.f;
  #pragma unroll
  for (int j=0;j<16;j++){
    f32x4 cw = cw4[j];
    float vv = bf2f((u16)(j<8 ? v0[j] : v1[j-8]));
    float qv = (j<4)? q0[j] : (j<8)? q1[j-4] : (j<12)? q2[j-8] : q3[j-12];
    float x = qv + vv + am*cw[0] + ac*cw[1] + ap*cw[2];
    sum += ftanh(x)*cw[3];
  }
  #pragma unroll
  for (int o=32;o;o>>=1) sum += __shfl_xor(sum, o);
  if (lane==0) energy[b*S_+s] = sum;
}

// softmax over s, write attn, then context[b,d] = sum_s attn*enc -> qcat[:,1024:2048]
__global__ __launch_bounds__(1024) void k_smctx(const float* __restrict__ energy, float* __restrict__ attn_out,
    const u16* __restrict__ enc_bf, u16* __restrict__ qcat_t)
{
  int b = blockIdx.x, tid = threadIdx.x;
  __shared__ float aw[S_];
  __shared__ float red[16];
  float e = (tid < S_) ? energy[b*S_ + tid] : -3.0e38f;
  float m = e;
  #pragma unroll
  for (int o=32;o;o>>=1) m = fmaxf(m, __shfl_xor(m, o));
  if ((tid&63)==0) red[tid>>6] = m;
  __syncthreads();
  float mx = red[0];
  #pragma unroll
  for (int i=1;i<16;i++) mx = fmaxf(mx, red[i]);
  __syncthreads();
  float ex = (tid < S_) ? __expf(e - mx) : 0.f;
  float sl = ex;
  #pragma unroll
  for (int o=32;o;o>>=1) sl += __shfl_xor(sl, o);
  if ((tid&63)==0) red[tid>>6] = sl;
  __syncthreads();
  float st = 0.f;
  #pragma unroll
  for (int i=0;i<16;i++) st += red[i];
  float inv = 1.f/st;
  if (tid < S_){ float a = ex*inv; aw[tid] = a; attn_out[b*S_+tid] = a; }
  __syncthreads();
  float a0=0.f,a1=0.f,a2=0.f,a3=0.f;
  const u16* ep = enc_bf + (size_t)b*S_*D_ + tid;
  #pragma unroll 2
  for (int s=0;s<S_;s+=4){
    a0 += aw[s]   * bf2f(ep[(size_t)(s)  *D_]);
    a1 += aw[s+1] * bf2f(ep[(size_t)(s+1)*D_]);
    a2 += aw[s+2] * bf2f(ep[(size_t)(s+2)*D_]);
    a3 += aw[s+3] * bf2f(ep[(size_t)(s+3)*D_]);
  }
  qcat_t[b*2048 + D_ + tid] = f2bf(a0+a1+a2+a3);
}

// in-place log_softmax over V per row of out
__global__ __launch_bounds__(256) void k_logsm(float* __restrict__ out){
  int row = blockIdx.x, tid = threadIdx.x;
  float* p = out + (size_t)row*V_;
  __shared__ float red[4];
  float mx = -3.0e38f;
  for (int v=tid; v<V_; v+=256) mx = fmaxf(mx, p[v]);
  #pragma unroll
  for (int o=32;o;o>>=1) mx = fmaxf(mx, __shfl_xor(mx,o));
  if ((tid&63)==0) red[tid>>6]=mx;
  __syncthreads();
  mx = fmaxf(fmaxf(red[0],red[1]),fmaxf(red[2],red[3]));
  __syncthreads();
  float s = 0.f;
  for (int v=tid; v<V_; v+=256) s += __expf(p[v]-mx);
  #pragma unroll
  for (int o=32;o;o>>=1) s += __shfl_xor(s,o);
  if ((tid&63)==0) red[tid>>6]=s;
  __syncthreads();
  float lz = mx + __logf(red[0]+red[1]+red[2]+red[3]);
  for (int v=tid; v<V_; v+=256) p[v] -= lz;
}

// ---------------- host ----------------
extern "C" void kernel_launch(void* const* d_in, const int* in_sizes, int n_in,
                              void* d_out, int out_size, void* d_ws, size_t ws_size,
                              hipStream_t stream)
{
  const float* enc   = (const float*)d_in[0];
  const int*   tgt   = (const int*)  d_in[1];
  const float* emb   = (const float*)d_in[2];
  const float* Wih   = (const float*)d_in[3];
  const float* Whh   = (const float*)d_in[4];
  const float* bih   = (const float*)d_in[5];
  const float* bhh   = (const float*)d_in[6];
  const float* Wcv   = (const float*)d_in[7];
  const float* bcv   = (const float*)d_in[8];
  const float* Wq    = (const float*)d_in[9];
  const float* Wvm   = (const float*)d_in[10];
  const float* abias = (const float*)d_in[11];
  const float* fcw   = (const float*)d_in[12];
  // d_in[13] fc_attn_b: constant shift before softmax -> no effect, unused
  const float* fc1w  = (const float*)d_in[14];
  const float* fc1b  = (const float*)d_in[15];
  const float* fc2w  = (const float*)d_in[16];
  const float* fc2b  = (const float*)d_in[17];
  float* out = (float*)d_out;

  char* base = (char*)d_ws; size_t off = 0;
  auto A = [&](size_t nbytes)->char*{ char* q = base + off; off += (nbytes + 255) & ~(size_t)255; return q; };
  u16* enc_bf  = (u16*)A(8388608ull*2);
  u16* Wv_bf   = (u16*)A(1048576ull*2);
  u16* Wih0_bf = (u16*)A(4194304ull*2);
  u16* W1cat   = (u16*)A(8388608ull*2);
  u16* Whh0_bf = (u16*)A(4194304ull*2);
  u16* Wq_bf   = (u16*)A(1048576ull*2);
  u16* fc1w_bf = (u16*)A(2097152ull*2);
  u16* fc2w_bf = (u16*)A(10240000ull*2);
  u16* embA    = (u16*)A(4194304ull*2);   // reused as hid after the loop
  u16* X0      = (u16*)A(16777216ull*2);  // (T,32,4096) bf16
  u16* vpb     = (u16*)A(8388608ull*2);   // bf16(vproj + bconv + attn_bias)
  u16* qcat    = (u16*)A(8388608ull*2);   // (T*32, 2048) = [q | context]
  float* bias0 = (float*)A(4096*4);
  float* bias1 = (float*)A(4096*4);
  float* biasE = (float*)A(1024*4);
  float* convw = (float*)A(4096*4);       // [d][{Wc0,Wc1,Wc2,fcw}]
  float* qp    = (float*)A(32768*4);
  float* energy= (float*)A(8192*4);
  float* c0    = (float*)A(32768*4);
  float* c1    = (float*)A(32768*4);
  float* attn  = (float*)A(2*8192*4);
  u16* hA      = (u16*)A(2*32768*2);
  u16* hB      = (u16*)A(2*32768*2);
  u16* hid     = embA;

  // zero recurrent state (harness does not re-poison between replays)
  hipMemsetAsync(c0, 0, 32768*4, stream);
  hipMemsetAsync(c1, 0, 32768*4, stream);
  hipMemsetAsync(attn, 0, 2*8192*4, stream);
  hipMemsetAsync(hA, 0, 2*32768*2, stream);
  hipMemsetAsync(hB, 0, 2*32768*2, stream);

  // prep: bf16 casts, fused bias/conv tables, embedding gather
  k_cast<<<2048,256,0,stream>>>(enc,  enc_bf,  8388608);
  k_cast<<<1024,256,0,stream>>>(Wih,  Wih0_bf, 4194304);
  k_cast<<<1024,256,0,stream>>>(Whh,  Whh0_bf, 4194304);
  k_cast<<<512,256,0,stream>>>(Wq,    Wq_bf,   1048576);
  k_cast<<<512,256,0,stream>>>(Wvm,   Wv_bf,   1048576);
  k_cast<<<512,256,0,stream>>>(fc1w,  fc1w_bf, 2097152);
  k_cast<<<2048,256,0,stream>>>(fc2w, fc2w_bf, 10240000);
  k_w1cat<<<2048,256,0,stream>>>(Wih + 4194304, Whh + 4194304, W1cat);
  k_bias<<<16,256,0,stream>>>(bih, bhh, bcv, abias, Wcv, fcw, bias0, bias1, biasE, convw);
  k_gather<<<4096,256,0,stream>>>(emb, tgt, embA);

  // vpb = bf16(enc @ Wv^T + (bconv + attn_bias))   (8192 x 1024 x 1024)
  k_gemm128<1,false><<<dim3(8,64),256,0,stream>>>(enc_bf, Wv_bf, biasE, vpb, 8192, 1024, 1024, 1024);
  // X0 = bf16(emb[targets] @ W_ih0^T + (b_ih0+b_hh0))  (4096 x 4096 x 1024)
  k_gemm128<1,false><<<dim3(32,32),256,0,stream>>>(embA, Wih0_bf, bias0, X0, 4096, 4096, 1024, 4096);

  // sequential decode: 5 kernels per step
  for (int t = 0; t < T_; ++t){
    int pi = t & 1, po = pi ^ 1;
    u16* qcat_t = qcat + (size_t)t*B_*2048;
    k_gates0<<<64,256,0,stream>>>(hA + pi*32768, Whh0_bf, X0 + (size_t)t*B_*4096, c0, hA + po*32768);
    k_gates1<<<64,256,0,stream>>>(hA + po*32768, hB + pi*32768, W1cat, bias1, c1, hB + po*32768, qcat_t);
    k_qp<<<16,256,0,stream>>>(hB + po*32768, Wq_bf, qp);
    k_energy<<<2048,256,0,stream>>>(vpb, qp, attn + pi*8192, convw, energy);
    k_smctx<<<32,1024,0,stream>>>(energy, attn + po*8192, enc_bf, qcat_t);
  }

  // hid = tanh(qcat @ fc1w^T + fc1b)   (4096 x 1024 x 2048)
  k_gemm128<2,false><<<dim3(8,32),256,0,stream>>>(qcat, fc1w_bf, fc1b, hid, 4096, 1024, 2048, 1024);
  // logits = hid @ fc2w^T + fc2b -> out[b][t][v]  (4096 x 10000 x 1024, row swizzle (t,b)->(b,t))
  k_gemm128<0,true><<<dim3(79,32),256,0,stream>>>(hid, fc2w_bf, fc2b, out, 4096, V_, 1024, V_);
  // in-place log_softmax over V
  k_logsm<<<4096,256,0,stream>>>(out);
}